// Round 7
// baseline (156.119 us; speedup 1.0000x reference)
//
#include <hip/hip_runtime.h>

// bicon_loss R7: XCD slab swizzle + row-pair per thread.
// R6 evidence: inputs L3-resident (hbm ~0), VALU 22%, 7 B/cy/CU delivered
// => CU miss-queue x L3-latency bound; 2.9-row blocks put y-halos on other
// XCDs' L2. Fix: (a) contiguous 121-block slab per XCD so halos hit local
// L2; (b) 8 px/thread (rows y0,y0+1) for 2x MLP and 34% (not 69%) halo.

#define EPSF 1e-7f

constexpr int B = 16, H = 352, W = 352;
constexpr int HW = H * W;        // 123904
constexpr int N = B * HW;        // 1982464
constexpr int W4 = W / 4;        // 88
constexpr int HW8 = HW / 8;      // 15488 (quad-cols x row-pairs)
constexpr int NT = N / 8;        // 247808 threads
constexpr int NBLK = NT / 256;   // 968 = 8 * 121
constexpr int PER_XCD = NBLK / 8;// 121

typedef float f4 __attribute__((ext_vector_type(4)));
typedef int   i4 __attribute__((ext_vector_type(4)));

__device__ __forceinline__ float rcpf(float x) { return __builtin_amdgcn_rcpf(x); }

__device__ __forceinline__ f4 sigmoid4(f4 x) {
    f4 r;
    r.x = rcpf(1.0f + __expf(-x.x));
    r.y = rcpf(1.0f + __expf(-x.y));
    r.z = rcpf(1.0f + __expf(-x.z));
    r.w = rcpf(1.0f + __expf(-x.w));
    return r;
}
__device__ __forceinline__ f4 max4(f4 a, f4 b) {
    f4 r; r.x=fmaxf(a.x,b.x); r.y=fmaxf(a.y,b.y); r.z=fmaxf(a.z,b.z); r.w=fmaxf(a.w,b.w); return r;
}
__device__ __forceinline__ f4 min4(f4 a, f4 b) {
    f4 r; r.x=fminf(a.x,b.x); r.y=fminf(a.y,b.y); r.z=fminf(a.z,b.z); r.w=fminf(a.w,b.w); return r;
}
__device__ __forceinline__ f4 sel4(i4 q, f4 a, f4 b) {
    f4 r; r.x=q.x?a.x:b.x; r.y=q.y?a.y:b.y; r.z=q.z?a.z:b.z; r.w=q.w?a.w:b.w; return r;
}
__device__ __forceinline__ f4 loadu4(const float* p) {   // 4B-aligned 16B load
    f4 v; __builtin_memcpy(&v, p, sizeof(f4)); return v;
}

__device__ __forceinline__ float finish_pixel(float glo, float pmin, int sc,
                                              float t, float cp, float ba, float bb) {
    const float edge = (sc < 8 && sc > 0) ? 1.0f : 0.0f;
    float dec = glo * (1.0f - edge) + (1.0f - pmin) * edge;
    dec = fminf(fmaxf(dec, EPSF), 1.0f - EPSF);
    const float de = -(t * __logf(dec) + (1.0f - t) * __logf(1.0f - dec));
    return de - 0.8f * __logf(cp) - 0.2f * (__logf(ba) + __logf(bb));
}

// One quad's 8-direction accumulation. S* are pre-sigmoided neighbor quads.
#define DIRS(P, Q, S, DX, RMASK, BI) {                                        \
        f4 s = (S);                                                           \
        s *= (RMASK);                                                         \
        if ((DX) == 1)  s.x *= lm;                                            \
        if ((DX) == -1) s.w *= rm;                                            \
        const f4 v = (P) * s;                                                 \
        glo  = max4(glo,  v);                                                 \
        pmin = min4(pmin, v);                                                 \
        conprod *= sel4((Q), (P), 1.0f - (P));                                \
        BI *= sel4((Q), max4(v, (f4){EPSF,EPSF,EPSF,EPSF}), 1.0f - v);        \
    }

__global__ __launch_bounds__(256, 4) void bicon_loss_kernel(
    const float* __restrict__ c_map,    // [B,8,H,W]
    const float* __restrict__ target,   // [B,1,H,W]
    const int*   __restrict__ con,      // [B,8,H,W] in {0,1}
    float* __restrict__ ws)             // [NBLK] partial sums
{
    // XCD slab swizzle: hw blocks are issued round-robin over 8 XCDs
    // (xcd = blockIdx%8); give each XCD a contiguous slab of logical blocks
    // so y-halo rows are in the local L2.
    const int lb  = (blockIdx.x & 7) * PER_XCD + (blockIdx.x >> 3);
    const int tid = lb * 256 + threadIdx.x;         // < NT exactly
    const int b   = tid / HW8;
    const int rem = tid - b * HW8;
    const int rp  = rem / W4;            // row-pair index 0..175
    const int xq  = rem - rp * W4;
    const int y0  = rp * 2;              // even row (A); B = y0+1 (odd)
    const int x0  = xq * 4;

    const float* __restrict__ cm = c_map + (size_t)b * 8 * HW + y0 * W + x0;
    const int*   __restrict__ cn = con   + (size_t)b * 8 * HW + y0 * W + x0;
    const float* __restrict__ tg = target + (size_t)b * HW + y0 * W + x0;

    const float lm  = (xq == 0)      ? 0.0f : 1.0f;  // left edge  (DX=+1)
    const float rm  = (xq == W4 - 1) ? 0.0f : 1.0f;  // right edge (DX=-1)
    const float tmA = (y0 == 0)      ? 0.0f : 1.0f;  // A top row   (DY=+1)
    const float bmB = (y0 == H - 2)  ? 0.0f : 1.0f;  // B bottom row(DY=-1)

    // ---------------- phase A: burst loads (25 x 16B) ----------------
    const f4 cA0 = *(const f4*)(cm + 0 * HW);
    const f4 cA1 = *(const f4*)(cm + 1 * HW);
    const f4 cA2 = *(const f4*)(cm + 2 * HW);
    const f4 cA3 = *(const f4*)(cm + 3 * HW);
    const f4 cA4 = *(const f4*)(cm + 4 * HW);
    const f4 cA5 = *(const f4*)(cm + 5 * HW);
    const f4 cA6 = *(const f4*)(cm + 6 * HW);
    const f4 cA7 = *(const f4*)(cm + 7 * HW);
    const f4 cB1 = *(const f4*)(cm + 1 * HW + W);    // A dir6 neighbor == B center ch1
    const f4 nA0 = loadu4(cm + 7 * HW - W - 1);
    const f4 nA1 = *(const f4*)(cm + 6 * HW - W);
    const f4 nA2 = loadu4(cm + 5 * HW - W + 1);
    const f4 nA3 = loadu4(cm + 4 * HW - 1);
    const f4 nA4 = loadu4(cm + 3 * HW + 1);
    const f4 nA5 = loadu4(cm + 2 * HW + W - 1);
    const f4 nA7 = loadu4(cm + 0 * HW + W + 1);
    const i4 qA0 = *(const i4*)(cn + 0 * HW);
    const i4 qA1 = *(const i4*)(cn + 1 * HW);
    const i4 qA2 = *(const i4*)(cn + 2 * HW);
    const i4 qA3 = *(const i4*)(cn + 3 * HW);
    const i4 qA4 = *(const i4*)(cn + 4 * HW);
    const i4 qA5 = *(const i4*)(cn + 5 * HW);
    const i4 qA6 = *(const i4*)(cn + 6 * HW);
    const i4 qA7 = *(const i4*)(cn + 7 * HW);
    const f4 tA  = *(const f4*)(tg);

    const f4 pA0 = sigmoid4(cA0);
    const f4 pA1 = sigmoid4(cA1);
    const f4 pA2 = sigmoid4(cA2);
    const f4 pA3 = sigmoid4(cA3);
    const f4 pA4 = sigmoid4(cA4);
    const f4 pA5 = sigmoid4(cA5);
    const f4 pA6 = sigmoid4(cA6);
    const f4 pA7 = sigmoid4(cA7);
    const f4 pB1 = sigmoid4(cB1);                    // reused as B center

    float part;
    {
        f4 conprod = {1.f,1.f,1.f,1.f};
        f4 biA     = {1.f,1.f,1.f,1.f};
        f4 biB     = {1.f,1.f,1.f,1.f};
        f4 glo     = {-1e30f,-1e30f,-1e30f,-1e30f};
        f4 pmin    = { 1e30f, 1e30f, 1e30f, 1e30f};
        DIRS(pA0, qA0, sigmoid4(nA0),  1, tmA,  biA)
        DIRS(pA1, qA1, sigmoid4(nA1),  0, tmA,  biA)
        DIRS(pA2, qA2, sigmoid4(nA2), -1, tmA,  biA)
        DIRS(pA3, qA3, sigmoid4(nA3),  1, 1.0f, biA)
        DIRS(pA4, qA4, sigmoid4(nA4), -1, 1.0f, biB)
        DIRS(pA5, qA5, sigmoid4(nA5),  1, 1.0f, biB)
        DIRS(pA6, qA6, pB1,            0, 1.0f, biB)
        DIRS(pA7, qA7, sigmoid4(nA7), -1, 1.0f, biB)
        const i4 sc = qA0 + qA1 + qA2 + qA3 + qA4 + qA5 + qA6 + qA7;
        part = finish_pixel(glo.x, pmin.x, sc.x, tA.x, conprod.x, biA.x, biB.x)
             + finish_pixel(glo.y, pmin.y, sc.y, tA.y, conprod.y, biA.y, biB.y)
             + finish_pixel(glo.z, pmin.z, sc.z, tA.z, conprod.z, biA.z, biB.z)
             + finish_pixel(glo.w, pmin.w, sc.w, tA.w, conprod.w, biA.w, biB.w);
    }

    // ---------------- phase B: burst loads (23 x 16B) ----------------
    const float* cmB = cm + W;
    const int*   cnB = cn + W;
    const f4 cB0 = *(const f4*)(cmB + 0 * HW);
    const f4 cB2 = *(const f4*)(cmB + 2 * HW);
    const f4 cB3 = *(const f4*)(cmB + 3 * HW);
    const f4 cB4 = *(const f4*)(cmB + 4 * HW);
    const f4 cB5 = *(const f4*)(cmB + 5 * HW);
    const f4 cB6 = *(const f4*)(cmB + 6 * HW);
    const f4 cB7 = *(const f4*)(cmB + 7 * HW);
    const f4 nB0 = loadu4(cmB + 7 * HW - W - 1);     // = cm + 7HW - 1
    const f4 nB2 = loadu4(cmB + 5 * HW - W + 1);
    const f4 nB3 = loadu4(cmB + 4 * HW - 1);
    const f4 nB4 = loadu4(cmB + 3 * HW + 1);
    const f4 nB5 = loadu4(cmB + 2 * HW + W - 1);
    const f4 nB6 = *(const f4*)(cmB + 1 * HW + W);
    const f4 nB7 = loadu4(cmB + 0 * HW + W + 1);
    const i4 qB0 = *(const i4*)(cnB + 0 * HW);
    const i4 qB1 = *(const i4*)(cnB + 1 * HW);
    const i4 qB2 = *(const i4*)(cnB + 2 * HW);
    const i4 qB3 = *(const i4*)(cnB + 3 * HW);
    const i4 qB4 = *(const i4*)(cnB + 4 * HW);
    const i4 qB5 = *(const i4*)(cnB + 5 * HW);
    const i4 qB6 = *(const i4*)(cnB + 6 * HW);
    const i4 qB7 = *(const i4*)(cnB + 7 * HW);
    const f4 tB  = *(const f4*)(tg + W);

    const f4 pB0 = sigmoid4(cB0);
    const f4 pB2 = sigmoid4(cB2);
    const f4 pB3 = sigmoid4(cB3);
    const f4 pB4 = sigmoid4(cB4);
    const f4 pB5 = sigmoid4(cB5);
    const f4 pB6 = sigmoid4(cB6);
    const f4 pB7 = sigmoid4(cB7);

    {
        f4 conprod = {1.f,1.f,1.f,1.f};
        f4 biA     = {1.f,1.f,1.f,1.f};
        f4 biB     = {1.f,1.f,1.f,1.f};
        f4 glo     = {-1e30f,-1e30f,-1e30f,-1e30f};
        f4 pmin    = { 1e30f, 1e30f, 1e30f, 1e30f};
        // B dirs 0-2 (DY=+1) read row y0 >= 0: always in bounds.
        DIRS(pB0, qB0, sigmoid4(nB0),  1, 1.0f, biA)
        DIRS(pB1, qB1, pA6,            0, 1.0f, biA)   // ch6 @ y0 = A center
        DIRS(pB2, qB2, sigmoid4(nB2), -1, 1.0f, biA)
        DIRS(pB3, qB3, sigmoid4(nB3),  1, 1.0f, biA)
        DIRS(pB4, qB4, sigmoid4(nB4), -1, 1.0f, biB)
        DIRS(pB5, qB5, sigmoid4(nB5),  1, bmB,  biB)
        DIRS(pB6, qB6, sigmoid4(nB6),  0, bmB,  biB)
        DIRS(pB7, qB7, sigmoid4(nB7), -1, bmB,  biB)
        const i4 sc = qB0 + qB1 + qB2 + qB3 + qB4 + qB5 + qB6 + qB7;
        part += finish_pixel(glo.x, pmin.x, sc.x, tB.x, conprod.x, biA.x, biB.x)
              + finish_pixel(glo.y, pmin.y, sc.y, tB.y, conprod.y, biA.y, biB.y)
              + finish_pixel(glo.z, pmin.z, sc.z, tB.z, conprod.z, biA.z, biB.z)
              + finish_pixel(glo.w, pmin.w, sc.w, tB.w, conprod.w, biA.w, biB.w);
    }

    // wave64 shuffle reduction
    #pragma unroll
    for (int off = 32; off > 0; off >>= 1)
        part += __shfl_down(part, off, 64);

    __shared__ float wsum[4];
    const int lane = threadIdx.x & 63;
    const int wid  = threadIdx.x >> 6;
    if (lane == 0) wsum[wid] = part;
    __syncthreads();
    if (threadIdx.x == 0) {
        ws[blockIdx.x] = wsum[0] + wsum[1] + wsum[2] + wsum[3];  // plain store
    }
}

// Stage 2: one block sums the NBLK partials and writes the scalar output.
__global__ __launch_bounds__(256) void reduce_partials_kernel(
    const float* __restrict__ ws, float* __restrict__ out)
{
    float s = 0.0f;
    for (int i = threadIdx.x; i < NBLK; i += 256) s += ws[i];
    #pragma unroll
    for (int off = 32; off > 0; off >>= 1)
        s += __shfl_down(s, off, 64);
    __shared__ float wsum[4];
    const int lane = threadIdx.x & 63;
    const int wid  = threadIdx.x >> 6;
    if (lane == 0) wsum[wid] = s;
    __syncthreads();
    if (threadIdx.x == 0) out[0] = wsum[0] + wsum[1] + wsum[2] + wsum[3];
}

extern "C" void kernel_launch(void* const* d_in, const int* in_sizes, int n_in,
                              void* d_out, int out_size, void* d_ws, size_t ws_size,
                              hipStream_t stream) {
    const float* c_map  = (const float*)d_in[0];
    const float* target = (const float*)d_in[1];
    const int*   con    = (const int*)d_in[2];
    float* out = (float*)d_out;
    float* ws  = (float*)d_ws;   // NBLK floats

    bicon_loss_kernel<<<NBLK, 256, 0, stream>>>(c_map, target, con, ws);
    reduce_partials_kernel<<<1, 256, 0, stream>>>(ws, out);
}

// Round 8
// 151.419 us; speedup vs baseline: 1.0310x; 1.0310x over previous
//
#include <hip/hip_runtime.h>

// bicon_loss R8: R6 structure + amdgpu_waves_per_eu(4,4).
// R5-R7 evidence: time == FETCH / 1.8 TB/s in every round (HBM-latency
// bound, ~2.6 wave-loads outstanding per CU). The compiler pins VGPR=64
// (schedules for 8 waves/EU) and splits the 26-load burst into chunks of
// ~4. waves_per_eu(4,4) sets max=4 so the scheduler may use 128 VGPRs and
// keep the whole burst in flight. Single-variable change vs R6 (46 us).

#define EPSF 1e-7f

constexpr int B = 16, H = 352, W = 352;
constexpr int HW = H * W;        // 123904
constexpr int N = B * HW;        // 1982464
constexpr int W4 = W / 4;        // 88
constexpr int HW4 = HW / 4;      // 30976
constexpr int NQ = N / 4;        // 495616 = 1936 * 256 exactly
constexpr int NBLK = NQ / 256;   // 1936

typedef float f4 __attribute__((ext_vector_type(4)));
typedef int   i4 __attribute__((ext_vector_type(4)));

__device__ __forceinline__ float rcpf(float x) { return __builtin_amdgcn_rcpf(x); }

__device__ __forceinline__ f4 sigmoid4(f4 x) {
    f4 r;
    r.x = rcpf(1.0f + __expf(-x.x));
    r.y = rcpf(1.0f + __expf(-x.y));
    r.z = rcpf(1.0f + __expf(-x.z));
    r.w = rcpf(1.0f + __expf(-x.w));
    return r;
}
__device__ __forceinline__ f4 max4(f4 a, f4 b) {
    f4 r; r.x=fmaxf(a.x,b.x); r.y=fmaxf(a.y,b.y); r.z=fmaxf(a.z,b.z); r.w=fmaxf(a.w,b.w); return r;
}
__device__ __forceinline__ f4 min4(f4 a, f4 b) {
    f4 r; r.x=fminf(a.x,b.x); r.y=fminf(a.y,b.y); r.z=fminf(a.z,b.z); r.w=fminf(a.w,b.w); return r;
}
__device__ __forceinline__ f4 sel4(i4 q, f4 a, f4 b) {
    f4 r; r.x=q.x?a.x:b.x; r.y=q.y?a.y:b.y; r.z=q.z?a.z:b.z; r.w=q.w?a.w:b.w; return r;
}
__device__ __forceinline__ f4 loadu4(const float* p) {   // 4B-aligned 16B load
    f4 v; __builtin_memcpy(&v, p, sizeof(f4)); return v;
}

__device__ __forceinline__ float finish_pixel(float glo, float pmin, int sc,
                                              float t, float cp, float ba, float bb) {
    const float edge = (sc < 8 && sc > 0) ? 1.0f : 0.0f;
    float dec = glo * (1.0f - edge) + (1.0f - pmin) * edge;
    dec = fminf(fmaxf(dec, EPSF), 1.0f - EPSF);
    const float de = -(t * __logf(dec) + (1.0f - t) * __logf(1.0f - dec));
    return de - 0.8f * __logf(cp) - 0.2f * (__logf(ba) + __logf(bb));
}

__global__ __launch_bounds__(256)
__attribute__((amdgpu_waves_per_eu(4, 4)))
void bicon_loss_kernel(
    const float* __restrict__ c_map,    // [B,8,H,W]
    const float* __restrict__ target,   // [B,1,H,W]
    const int*   __restrict__ con,      // [B,8,H,W] in {0,1}
    float* __restrict__ ws)             // [NBLK] partial sums
{
    const int tid = blockIdx.x * blockDim.x + threadIdx.x;   // < NQ exactly
    const int b  = tid / HW4;
    const int rq = tid - b * HW4;
    const int y  = rq / W4;
    const int xq = rq - y * W4;
    const int x0 = xq * 4;

    const float* __restrict__ cm = c_map + (size_t)b * 8 * HW + y * W + x0;
    const int*   __restrict__ cn = con   + (size_t)b * 8 * HW + y * W + x0;

    // ---------- burst load phase: 26 independent 16B loads ----------
    const f4 c0 = *(const f4*)(cm + 0 * HW);
    const f4 c1 = *(const f4*)(cm + 1 * HW);
    const f4 c2 = *(const f4*)(cm + 2 * HW);
    const f4 c3 = *(const f4*)(cm + 3 * HW);
    const f4 c4 = *(const f4*)(cm + 4 * HW);
    const f4 c5 = *(const f4*)(cm + 5 * HW);
    const f4 c6 = *(const f4*)(cm + 6 * HW);
    const f4 c7 = *(const f4*)(cm + 7 * HW);
    // neighbor raw values: dir i reads channel 7-i at (y-DY, x-DX)
    const f4 n0 = loadu4(cm + 7 * HW - 1 * W - 1);   // DX=+1, DY=+1
    const f4 n1 = *(const f4*)(cm + 6 * HW - 1 * W); // DX=0,  DY=+1
    const f4 n2 = loadu4(cm + 5 * HW - 1 * W + 1);   // DX=-1, DY=+1
    const f4 n3 = loadu4(cm + 4 * HW - 1);           // DX=+1, DY=0
    const f4 n4 = loadu4(cm + 3 * HW + 1);           // DX=-1, DY=0
    const f4 n5 = loadu4(cm + 2 * HW + 1 * W - 1);   // DX=+1, DY=-1
    const f4 n6 = *(const f4*)(cm + 1 * HW + 1 * W); // DX=0,  DY=-1
    const f4 n7 = loadu4(cm + 0 * HW + 1 * W + 1);   // DX=-1, DY=-1
    const i4 q0 = *(const i4*)(cn + 0 * HW);
    const i4 q1 = *(const i4*)(cn + 1 * HW);
    const i4 q2 = *(const i4*)(cn + 2 * HW);
    const i4 q3 = *(const i4*)(cn + 3 * HW);
    const i4 q4 = *(const i4*)(cn + 4 * HW);
    const i4 q5 = *(const i4*)(cn + 5 * HW);
    const i4 q6 = *(const i4*)(cn + 6 * HW);
    const i4 q7 = *(const i4*)(cn + 7 * HW);
    const f4 t4 = *(const f4*)(target + (size_t)b * HW + y * W + x0);

    // ---------- compute phase ----------
    const f4 p0 = sigmoid4(c0);
    const f4 p1 = sigmoid4(c1);
    const f4 p2 = sigmoid4(c2);
    const f4 p3 = sigmoid4(c3);
    const f4 p4 = sigmoid4(c4);
    const f4 p5 = sigmoid4(c5);
    const f4 p6 = sigmoid4(c6);
    const f4 p7 = sigmoid4(c7);

    const float lm = (xq == 0)      ? 0.0f : 1.0f;  // left edge  (DX=+1)
    const float rm = (xq == W4 - 1) ? 0.0f : 1.0f;  // right edge (DX=-1)
    const float tm = (y == 0)       ? 0.0f : 1.0f;  // top row    (DY=+1)
    const float bm = (y == H - 1)   ? 0.0f : 1.0f;  // bottom row (DY=-1)

    f4 conprod = {1.f,1.f,1.f,1.f};
    f4 biA     = {1.f,1.f,1.f,1.f};
    f4 biB     = {1.f,1.f,1.f,1.f};
    f4 glo     = {-1e30f,-1e30f,-1e30f,-1e30f};
    f4 pmin    = { 1e30f, 1e30f, 1e30f, 1e30f};

#define DIR(P, Q, NR, DX, RMASK, BI) {                                        \
        f4 s = sigmoid4(NR);                                                  \
        s *= (RMASK);                                                         \
        if ((DX) == 1)  s.x *= lm;                                            \
        if ((DX) == -1) s.w *= rm;                                            \
        const f4 v = (P) * s;                                                 \
        glo  = max4(glo,  v);                                                 \
        pmin = min4(pmin, v);                                                 \
        conprod *= sel4((Q), (P), 1.0f - (P));                                \
        BI *= sel4((Q), max4(v, (f4){EPSF,EPSF,EPSF,EPSF}), 1.0f - v);        \
    }
    DIR(p0, q0, n0,  1, tm, biA)
    DIR(p1, q1, n1,  0, tm, biA)
    DIR(p2, q2, n2, -1, tm, biA)
    DIR(p3, q3, n3,  1, 1.0f, biA)
    DIR(p4, q4, n4, -1, 1.0f, biB)
    DIR(p5, q5, n5,  1, bm, biB)
    DIR(p6, q6, n6,  0, bm, biB)
    DIR(p7, q7, n7, -1, bm, biB)
#undef DIR

    const i4 sc = q0 + q1 + q2 + q3 + q4 + q5 + q6 + q7;

    float part = finish_pixel(glo.x, pmin.x, sc.x, t4.x, conprod.x, biA.x, biB.x)
               + finish_pixel(glo.y, pmin.y, sc.y, t4.y, conprod.y, biA.y, biB.y)
               + finish_pixel(glo.z, pmin.z, sc.z, t4.z, conprod.z, biA.z, biB.z)
               + finish_pixel(glo.w, pmin.w, sc.w, t4.w, conprod.w, biA.w, biB.w);

    // wave64 shuffle reduction
    #pragma unroll
    for (int off = 32; off > 0; off >>= 1)
        part += __shfl_down(part, off, 64);

    __shared__ float wsum[4];
    const int lane = threadIdx.x & 63;
    const int wid  = threadIdx.x >> 6;
    if (lane == 0) wsum[wid] = part;
    __syncthreads();
    if (threadIdx.x == 0) {
        ws[blockIdx.x] = wsum[0] + wsum[1] + wsum[2] + wsum[3];  // plain store
    }
}

// Stage 2: one block sums the NBLK partials and writes the scalar output.
__global__ __launch_bounds__(256) void reduce_partials_kernel(
    const float* __restrict__ ws, float* __restrict__ out)
{
    float s = 0.0f;
    for (int i = threadIdx.x; i < NBLK; i += 256) s += ws[i];
    #pragma unroll
    for (int off = 32; off > 0; off >>= 1)
        s += __shfl_down(s, off, 64);
    __shared__ float wsum[4];
    const int lane = threadIdx.x & 63;
    const int wid  = threadIdx.x >> 6;
    if (lane == 0) wsum[wid] = s;
    __syncthreads();
    if (threadIdx.x == 0) out[0] = wsum[0] + wsum[1] + wsum[2] + wsum[3];
}

extern "C" void kernel_launch(void* const* d_in, const int* in_sizes, int n_in,
                              void* d_out, int out_size, void* d_ws, size_t ws_size,
                              hipStream_t stream) {
    const float* c_map  = (const float*)d_in[0];
    const float* target = (const float*)d_in[1];
    const int*   con    = (const int*)d_in[2];
    float* out = (float*)d_out;
    float* ws  = (float*)d_ws;   // NBLK floats

    bicon_loss_kernel<<<NBLK, 256, 0, stream>>>(c_map, target, con, ws);
    reduce_partials_kernel<<<1, 256, 0, stream>>>(ws, out);
}

// Round 9
// 150.658 us; speedup vs baseline: 1.0362x; 1.0050x over previous
//
#include <hip/hip_runtime.h>

// bicon_loss R9: LDS-staged sigmoid (f16), 1-D halo tiles.
// R8 evidence: dur invariant to HBM traffic (44us at 75MB and at 63KB
// fetched) => bound by vector-memory traffic (206 MB at ~18 GB/s/CU miss
// throughput). Fix: stage sigmoid(c_map) in LDS once per block (contiguous
// range + (W+1) halo both sides covers all 8 shifts), read neighbors from
// LDS. Traffic 104->78 B/px, exp halved, LDS-bound occupancy (2 blk/CU)
// frees the VGPR budget the scheduler refused to use in R5/R8.

#define EPSF 1e-7f

constexpr int B = 16, H = 352, W = 352;
constexpr int HW = H * W;              // 123904
constexpr int TILE_PX = 2816;          // 8 rows per block
constexpr int TILES = HW / TILE_PX;    // 44 (exact)
constexpr int NBLK = B * TILES;        // 704
constexpr int TILE_Q = TILE_PX / 4;    // 704 quads per block
constexpr int HALO = 384;              // >= W+1, multiple of 4
constexpr int STAGE_PX = TILE_PX + 2 * HALO;   // 3584 px per channel
constexpr int STAGE_Q  = STAGE_PX / 4;         // 896
constexpr int STAGE_ALL_Q = 8 * STAGE_Q;       // 7168
constexpr int SITER = STAGE_ALL_Q / 256;       // 28 staging iters/thread

typedef float    f4 __attribute__((ext_vector_type(4)));
typedef int      i4 __attribute__((ext_vector_type(4)));
typedef _Float16 h4 __attribute__((ext_vector_type(4)));

__device__ __forceinline__ float rcpf(float x) { return __builtin_amdgcn_rcpf(x); }

__device__ __forceinline__ f4 sigmoid4(f4 x) {
    f4 r;
    r.x = rcpf(1.0f + __expf(-x.x));
    r.y = rcpf(1.0f + __expf(-x.y));
    r.z = rcpf(1.0f + __expf(-x.z));
    r.w = rcpf(1.0f + __expf(-x.w));
    return r;
}
__device__ __forceinline__ f4 max4(f4 a, f4 b) {
    f4 r; r.x=fmaxf(a.x,b.x); r.y=fmaxf(a.y,b.y); r.z=fmaxf(a.z,b.z); r.w=fmaxf(a.w,b.w); return r;
}
__device__ __forceinline__ f4 min4(f4 a, f4 b) {
    f4 r; r.x=fminf(a.x,b.x); r.y=fminf(a.y,b.y); r.z=fminf(a.z,b.z); r.w=fminf(a.w,b.w); return r;
}
__device__ __forceinline__ f4 sel4(i4 m, f4 a, f4 b) {
    f4 r; r.x=m.x?a.x:b.x; r.y=m.y?a.y:b.y; r.z=m.z?a.z:b.z; r.w=m.w?a.w:b.w; return r;
}
__device__ __forceinline__ f4 cvt4(h4 h) {
    f4 r; r.x=(float)h.x; r.y=(float)h.y; r.z=(float)h.z; r.w=(float)h.w; return r;
}
// unaligned (element-granular) 4-wide f16 read from LDS
__device__ __forceinline__ f4 rd4(const _Float16* p) {
    f4 r; r.x=(float)p[0]; r.y=(float)p[1]; r.z=(float)p[2]; r.w=(float)p[3]; return r;
}

__device__ __forceinline__ float finish_pixel(float glo, float pmin, int sc,
                                              float t, float cp, float ba, float bb) {
    const float edge = (sc < 8 && sc > 0) ? 1.0f : 0.0f;
    float dec = glo * (1.0f - edge) + (1.0f - pmin) * edge;
    dec = fminf(fmaxf(dec, EPSF), 1.0f - EPSF);
    const float de = -(t * __logf(dec) + (1.0f - t) * __logf(1.0f - dec));
    return de - 0.8f * __logf(cp) - 0.2f * (__logf(ba) + __logf(bb));
}

__global__ __launch_bounds__(256) void bicon_loss_kernel(
    const float* __restrict__ c_map,    // [B,8,H,W]
    const float* __restrict__ target,   // [B,1,H,W]
    const int*   __restrict__ con,      // [B,8,H,W] in {0,1}
    float* __restrict__ ws)             // [NBLK] partial sums
{
    __shared__ _Float16 Lh[8 * STAGE_PX];   // 57344 B: sigmoid(c_map), f16
    __shared__ float wsum[4];

    const int blk  = blockIdx.x;
    const int b    = blk / TILES;
    const int tile = blk - b * TILES;
    const int s    = tile * TILE_PX;        // first pixel of tile (row-aligned)
    const int s0   = s - HALO;              // staged range start (may be <0)

    const float* __restrict__ cmb = c_map + (size_t)b * 8 * HW;
    const int*   __restrict__ cnb = con   + (size_t)b * 8 * HW;
    const float* __restrict__ tgb = target + (size_t)b * HW;

    // ---------------- staging: sigmoid of tile+halo, all 8 channels ----------
    // Clamped loads at image edges land on valid rows; every staged entry that
    // maps out-of-image is only ever consumed under a tm/bm/lm/rm zero mask.
    #pragma unroll
    for (int k = 0; k < SITER; ++k) {
        const int q   = threadIdx.x + k * 256;   // 0..7167
        const int ch  = q / STAGE_Q;
        const int idx = q - ch * STAGE_Q;
        int px = s0 + idx * 4;
        px = px < 0 ? 0 : (px > HW - 4 ? HW - 4 : px);
        const f4 v = *(const f4*)(cmb + ch * HW + px);
        const f4 p = sigmoid4(v);
        h4 hp; hp.x=(_Float16)p.x; hp.y=(_Float16)p.y; hp.z=(_Float16)p.z; hp.w=(_Float16)p.w;
        *(h4*)(&Lh[q * 4]) = hp;                 // 8B-aligned ds_write_b64
    }
    __syncthreads();

    // ---------------- compute: 704 quads, <=3 per thread ----------------
    float part = 0.0f;
    #pragma unroll
    for (int k = 0; k < 3; ++k) {
        const int qi = threadIdx.x + k * 256;
        if (qi < TILE_Q) {
            const int gp  = s + qi * 4;          // global pixel in image
            const int y   = gp / W;
            const int xq4 = (gp - y * W) >> 2;
            const float lm = (xq4 == 0)         ? 0.0f : 1.0f;
            const float rm = (xq4 == W / 4 - 1) ? 0.0f : 1.0f;
            const float tm = (y == 0)           ? 0.0f : 1.0f;
            const float bm = (y == H - 1)       ? 0.0f : 1.0f;
            const int l0 = qi * 4 + HALO;        // local staged index of gp

            // direct global loads (zero-reuse streams)
            const i4 g0 = *(const i4*)(cnb + 0 * HW + gp);
            const i4 g1 = *(const i4*)(cnb + 1 * HW + gp);
            const i4 g2 = *(const i4*)(cnb + 2 * HW + gp);
            const i4 g3 = *(const i4*)(cnb + 3 * HW + gp);
            const i4 g4 = *(const i4*)(cnb + 4 * HW + gp);
            const i4 g5 = *(const i4*)(cnb + 5 * HW + gp);
            const i4 g6 = *(const i4*)(cnb + 6 * HW + gp);
            const i4 g7 = *(const i4*)(cnb + 7 * HW + gp);
            const f4 t4 = *(const f4*)(tgb + gp);

            // centers (aligned h4 reads)
            const f4 p0 = cvt4(*(const h4*)&Lh[0 * STAGE_PX + l0]);
            const f4 p1 = cvt4(*(const h4*)&Lh[1 * STAGE_PX + l0]);
            const f4 p2 = cvt4(*(const h4*)&Lh[2 * STAGE_PX + l0]);
            const f4 p3 = cvt4(*(const h4*)&Lh[3 * STAGE_PX + l0]);
            const f4 p4 = cvt4(*(const h4*)&Lh[4 * STAGE_PX + l0]);
            const f4 p5 = cvt4(*(const h4*)&Lh[5 * STAGE_PX + l0]);
            const f4 p6 = cvt4(*(const h4*)&Lh[6 * STAGE_PX + l0]);
            const f4 p7 = cvt4(*(const h4*)&Lh[7 * STAGE_PX + l0]);
            // neighbors: dir i reads channel 7-i at offset -dy*W-dx
            const f4 n0 = rd4(&Lh[7 * STAGE_PX + l0 - W - 1]);
            const f4 n1 = cvt4(*(const h4*)&Lh[6 * STAGE_PX + l0 - W]);
            const f4 n2 = rd4(&Lh[5 * STAGE_PX + l0 - W + 1]);
            const f4 n3 = rd4(&Lh[4 * STAGE_PX + l0 - 1]);
            const f4 n4 = rd4(&Lh[3 * STAGE_PX + l0 + 1]);
            const f4 n5 = rd4(&Lh[2 * STAGE_PX + l0 + W - 1]);
            const f4 n6 = cvt4(*(const h4*)&Lh[1 * STAGE_PX + l0 + W]);
            const f4 n7 = rd4(&Lh[0 * STAGE_PX + l0 + W + 1]);

            f4 conprod = {1.f,1.f,1.f,1.f};
            f4 biA     = {1.f,1.f,1.f,1.f};
            f4 biB     = {1.f,1.f,1.f,1.f};
            f4 glo     = {-1e30f,-1e30f,-1e30f,-1e30f};
            f4 pmin    = { 1e30f, 1e30f, 1e30f, 1e30f};

#define DIR(P, G, S, DX, RMASK, BI) {                                         \
            f4 sv = (S);                                                      \
            sv *= (RMASK);                                                    \
            if ((DX) == 1)  sv.x *= lm;                                       \
            if ((DX) == -1) sv.w *= rm;                                       \
            const f4 v = (P) * sv;                                            \
            glo  = max4(glo,  v);                                             \
            pmin = min4(pmin, v);                                             \
            conprod *= sel4((G), (P), 1.0f - (P));                            \
            BI *= sel4((G), max4(v, (f4){EPSF,EPSF,EPSF,EPSF}), 1.0f - v);    \
        }
            DIR(p0, g0, n0,  1, tm,   biA)
            DIR(p1, g1, n1,  0, tm,   biA)
            DIR(p2, g2, n2, -1, tm,   biA)
            DIR(p3, g3, n3,  1, 1.0f, biA)
            DIR(p4, g4, n4, -1, 1.0f, biB)
            DIR(p5, g5, n5,  1, bm,   biB)
            DIR(p6, g6, n6,  0, bm,   biB)
            DIR(p7, g7, n7, -1, bm,   biB)
#undef DIR

            const i4 sc = g0 + g1 + g2 + g3 + g4 + g5 + g6 + g7;
            part += finish_pixel(glo.x, pmin.x, sc.x, t4.x, conprod.x, biA.x, biB.x)
                  + finish_pixel(glo.y, pmin.y, sc.y, t4.y, conprod.y, biA.y, biB.y)
                  + finish_pixel(glo.z, pmin.z, sc.z, t4.z, conprod.z, biA.z, biB.z)
                  + finish_pixel(glo.w, pmin.w, sc.w, t4.w, conprod.w, biA.w, biB.w);
        }
    }

    // wave64 shuffle reduction
    #pragma unroll
    for (int off = 32; off > 0; off >>= 1)
        part += __shfl_down(part, off, 64);

    const int lane = threadIdx.x & 63;
    const int wid  = threadIdx.x >> 6;
    if (lane == 0) wsum[wid] = part;
    __syncthreads();
    if (threadIdx.x == 0)
        ws[blockIdx.x] = wsum[0] + wsum[1] + wsum[2] + wsum[3];
}

// Stage 2: one block sums the NBLK partials and writes the scalar output.
__global__ __launch_bounds__(256) void reduce_partials_kernel(
    const float* __restrict__ ws, float* __restrict__ out)
{
    float s = 0.0f;
    for (int i = threadIdx.x; i < NBLK; i += 256) s += ws[i];
    #pragma unroll
    for (int off = 32; off > 0; off >>= 1)
        s += __shfl_down(s, off, 64);
    __shared__ float wsum[4];
    const int lane = threadIdx.x & 63;
    const int wid  = threadIdx.x >> 6;
    if (lane == 0) wsum[wid] = s;
    __syncthreads();
    if (threadIdx.x == 0) out[0] = wsum[0] + wsum[1] + wsum[2] + wsum[3];
}

extern "C" void kernel_launch(void* const* d_in, const int* in_sizes, int n_in,
                              void* d_out, int out_size, void* d_ws, size_t ws_size,
                              hipStream_t stream) {
    const float* c_map  = (const float*)d_in[0];
    const float* target = (const float*)d_in[1];
    const int*   con    = (const int*)d_in[2];
    float* out = (float*)d_out;
    float* ws  = (float*)d_ws;   // NBLK floats

    bicon_loss_kernel<<<NBLK, 256, 0, stream>>>(c_map, target, con, ws);
    reduce_partials_kernel<<<1, 256, 0, stream>>>(ws, out);
}